// Round 2
// baseline (71.089 us; speedup 1.0000x reference)
//
#include <hip/hip_runtime.h>
#include <hip/hip_bf16.h>
#include <type_traits>

// out = x @ M^T + c, with M = Wo @ Wv_sub (softmax row-sum == 1 collapses attn to v).
#define MROWS 4096   // B*S
#define EDIM  1024

typedef __attribute__((ext_vector_type(8))) __bf16 bf16x8;
typedef __attribute__((ext_vector_type(4))) float f32x4;
typedef __attribute__((ext_vector_type(8))) unsigned short ushort8;

__device__ __forceinline__ unsigned short f2bf(float f) {
    unsigned u = __builtin_bit_cast(unsigned, f);
    u += 0x7FFFu + ((u >> 16) & 1u);   // round-to-nearest-even
    return (unsigned short)(u >> 16);
}

__device__ __forceinline__ void async_load16(const void* g, void* l) {
    __builtin_amdgcn_global_load_lds(
        (const __attribute__((address_space(1))) void*)g,
        (__attribute__((address_space(3))) void*)l, 16, 0, 0);
}

// ---------------- fused prep kernel ----------------
// blocks [0,2048):    x (4096x1024 f32) -> bf16
// blocks [2048,2304): WvT[e,k] = bf16(Wqkv[vrow(k), e])   (16x16 tiles of 64x64)
// blocks [2304,2816): Wo -> bf16
// blocks [2816,2832): c[i] = bo[i] + sum_k Wo[i,k]*bqkv[vrow(k)]
__global__ __launch_bounds__(256) void prep(
    const float* __restrict__ x, const float* __restrict__ Wqkv,
    const float* __restrict__ bqkv, const float* __restrict__ Wo,
    const float* __restrict__ bo,
    unsigned short* __restrict__ x_bf, unsigned short* __restrict__ WvT,
    unsigned short* __restrict__ wo_bf, float* __restrict__ c)
{
    const int blk = blockIdx.x;
    const int t = threadIdx.x;
    if (blk < 2048) {                       // ---- cast x ----
        int i = blk * 256 + t;              // 8 elems per thread
        const float4* p = (const float4*)x + (size_t)i * 2;
        float4 a = p[0], b = p[1];
        ushort8 r;
        r[0] = f2bf(a.x); r[1] = f2bf(a.y); r[2] = f2bf(a.z); r[3] = f2bf(a.w);
        r[4] = f2bf(b.x); r[5] = f2bf(b.y); r[6] = f2bf(b.z); r[7] = f2bf(b.w);
        *((ushort8*)x_bf + i) = r;
    } else if (blk < 2304) {                // ---- build WvT ----
        __shared__ unsigned short tile[64][65];
        const int b = blk - 2048;
        const int eBase = (b & 15) * 64, kBase = (b >> 4) * 64;
        const int tx = t & 63, ty = t >> 6;
        #pragma unroll
        for (int r = ty; r < 64; r += 4) {
            int k = kBase + r;
            int j = ((k >> 6) * 192) + 128 + (k & 63);
            tile[r][tx] = f2bf(Wqkv[(size_t)j * EDIM + eBase + tx]);
        }
        __syncthreads();
        #pragma unroll
        for (int r = ty; r < 64; r += 4)
            WvT[(size_t)(eBase + r) * EDIM + kBase + tx] = tile[tx][r];
    } else if (blk < 2816) {                // ---- cast Wo ----
        int i = (blk - 2304) * 256 + t;
        const float4* p = (const float4*)Wo + (size_t)i * 2;
        float4 a = p[0], b = p[1];
        ushort8 r;
        r[0] = f2bf(a.x); r[1] = f2bf(a.y); r[2] = f2bf(a.z); r[3] = f2bf(a.w);
        r[4] = f2bf(b.x); r[5] = f2bf(b.y); r[6] = f2bf(b.z); r[7] = f2bf(b.w);
        *((ushort8*)wo_bf + i) = r;
    } else {                                // ---- fused bias c ----
        const int b = blk - 2816;           // 0..15
        const int wave = t >> 6, lane = t & 63;
        for (int r = 0; r < 16; ++r) {
            int row = b * 64 + wave * 16 + r;
            float s = 0.f;
            #pragma unroll
            for (int kk = 0; kk < 16; ++kk) {
                int k = kk * 64 + lane;
                int j = kk * 192 + 128 + lane;   // vrow(k)
                s += Wo[(size_t)row * EDIM + k] * bqkv[j];
            }
            #pragma unroll
            for (int off = 32; off > 0; off >>= 1) s += __shfl_down(s, off);
            if (lane == 0) c[row] = s + bo[row];
        }
    }
}

// ---------------- B^T-form bf16 MFMA GEMM, 128x128 tile, 8 waves ----------------
// C[m,n] = sum_k A[m,k]*B[n,k] (+bias[n]). 512 threads: wave grid 2x4,
// each wave owns 64x32 (acc[4][2]). XCD-aware bijective swizzle (NWG%8==0).
template<bool BIAS, typename OUT_T, int MD, int ND, int KD>
__global__ __launch_bounds__(512, 2) void gemm_bt(
    const unsigned short* __restrict__ A, const unsigned short* __restrict__ B,
    OUT_T* __restrict__ C, const float* __restrict__ bias)
{
    constexpr int BM = 128, BN = 128, BK = 64;
    constexpr int NBM = MD / BM, NBN = ND / BN, NWG = NBM * NBN;
    constexpr int CPX = NWG / 8;
    __shared__ unsigned short As[BM * BK];
    __shared__ unsigned short Bs[BN * BK];

    const int t = threadIdx.x;
    const int id = blockIdx.x;
    const int swz = (id & 7) * CPX + (id >> 3);     // XCD x owns one bn column-chunk
    const int bm = swz % NBM;
    const int bn = swz / NBM;

    const int lane = t & 63, wave = t >> 6;
    const int wr = wave >> 2, wc = wave & 3;        // 2 x 4 wave grid

    const int rsub = t >> 3;          // 0..63
    const int kb   = (t & 7) * 8;     // bf16-elem offset within BK

    const unsigned short* Ag = A + (size_t)(bm * BM + rsub) * KD + kb;
    const unsigned short* Bg = B + (size_t)(bn * BN + rsub) * KD + kb;

    f32x4 acc[4][2] = {};

    for (int k0 = 0; k0 < KD; k0 += BK) {
        __syncthreads();
        #pragma unroll
        for (int p = 0; p < 2; ++p)
            async_load16(Ag + (size_t)(p * 64) * KD + k0, &As[(rsub + p * 64) * BK + kb]);
        #pragma unroll
        for (int p = 0; p < 2; ++p)
            async_load16(Bg + (size_t)(p * 64) * KD + k0, &Bs[(rsub + p * 64) * BK + kb]);
        __syncthreads();   // compiler emits vmcnt(0) drain before barrier

        #pragma unroll
        for (int ks = 0; ks < 2; ++ks) {
            bf16x8 a[4], b[2];
            #pragma unroll
            for (int mi = 0; mi < 4; ++mi)
                a[mi] = *(const bf16x8*)&As[(wr * 64 + mi * 16 + (lane & 15)) * BK + ks * 32 + (lane >> 4) * 8];
            #pragma unroll
            for (int ni = 0; ni < 2; ++ni)
                b[ni] = *(const bf16x8*)&Bs[(wc * 32 + ni * 16 + (lane & 15)) * BK + ks * 32 + (lane >> 4) * 8];
            #pragma unroll
            for (int mi = 0; mi < 4; ++mi)
                #pragma unroll
                for (int ni = 0; ni < 2; ++ni)
                    acc[mi][ni] = __builtin_amdgcn_mfma_f32_16x16x32_bf16(
                        a[mi], b[ni], acc[mi][ni], 0, 0, 0);
        }
    }

    // C/D layout (m89/m91): col = lane&15, row = (lane>>4)*4 + reg.
    const int crow0 = bm * BM + wr * 64 + (lane >> 4) * 4;
    const int ccol0 = bn * BN + wc * 32 + (lane & 15);
    #pragma unroll
    for (int mi = 0; mi < 4; ++mi) {
        #pragma unroll
        for (int ni = 0; ni < 2; ++ni) {
            const int col = ccol0 + ni * 16;
            float bv = 0.f;
            if constexpr (BIAS) bv = bias[col];
            #pragma unroll
            for (int i = 0; i < 4; ++i) {
                const int row = crow0 + mi * 16 + i;
                float val = acc[mi][ni][i] + bv;
                if constexpr (std::is_same<OUT_T, float>::value)
                    C[(size_t)row * ND + col] = val;
                else
                    C[(size_t)row * ND + col] = f2bf(val);
            }
        }
    }
}

extern "C" void kernel_launch(void* const* d_in, const int* in_sizes, int n_in,
                              void* d_out, int out_size, void* d_ws, size_t ws_size,
                              hipStream_t stream) {
    const float* x    = (const float*)d_in[0];   // (2,2048,1024)
    const float* Wqkv = (const float*)d_in[1];   // (3072,1024)
    const float* bqkv = (const float*)d_in[2];   // (3072,)
    const float* Wo   = (const float*)d_in[3];   // (1024,1024)
    const float* bo   = (const float*)d_in[4];   // (1024,)
    float* out = (float*)d_out;                  // (2,2048,1024) f32

    char* ws = (char*)d_ws;
    unsigned short* x_bf  = (unsigned short*)(ws);                       // 8 MB
    unsigned short* wvt   = (unsigned short*)(ws + 8u  * 1024 * 1024);   // 2 MB
    unsigned short* wo_bf = (unsigned short*)(ws + 10u * 1024 * 1024);   // 2 MB
    unsigned short* m_bf  = (unsigned short*)(ws + 12u * 1024 * 1024);   // 2 MB
    float*          cvec  = (float*)(ws + 14u * 1024 * 1024);            // 4 KB

    // 1. all prep (cast x, gather/transpose Wv, cast Wo, fused bias) in one launch
    prep<<<2832, 256, 0, stream>>>(x, Wqkv, bqkv, Wo, bo, x_bf, wvt, wo_bf, cvec);
    // 2. M = Wo @ Wv_sub  (bf16 out)
    gemm_bt<false, unsigned short, EDIM, EDIM, EDIM><<<64, 512, 0, stream>>>(
        wo_bf, wvt, m_bf, nullptr);
    // 3. out = x @ M^T + c
    gemm_bt<true, float, MROWS, EDIM, EDIM><<<256, 512, 0, stream>>>(
        x_bf, m_bf, out, cvec);
}

// Round 3
// 60.105 us; speedup vs baseline: 1.1827x; 1.1827x over previous
//
#include <hip/hip_runtime.h>
#include <hip/hip_bf16.h>
#include <type_traits>

// out = x @ M^T + c, with M = Wo @ Wv_sub (softmax row-sum == 1 collapses attn to v).
#define MROWS 4096   // B*S
#define EDIM  1024

typedef __attribute__((ext_vector_type(8))) __bf16 bf16x8;
typedef __attribute__((ext_vector_type(4))) float f32x4;
typedef __attribute__((ext_vector_type(8))) unsigned short ushort8;

__device__ __forceinline__ unsigned short f2bf(float f) {
    unsigned u = __builtin_bit_cast(unsigned, f);
    u += 0x7FFFu + ((u >> 16) & 1u);   // round-to-nearest-even
    return (unsigned short)(u >> 16);
}

__device__ __forceinline__ void async_load16(const void* g, void* l) {
    __builtin_amdgcn_global_load_lds(
        (const __attribute__((address_space(1))) void*)g,
        (__attribute__((address_space(3))) void*)l, 16, 0, 0);
}

// cast 8 consecutive f32 -> bf16 at flat ushort8 index i
__device__ __forceinline__ void cast8(const float* __restrict__ in,
                                      unsigned short* __restrict__ out, int i) {
    const float4* p = (const float4*)in + (size_t)i * 2;
    float4 a = p[0], b = p[1];
    ushort8 r;
    r[0] = f2bf(a.x); r[1] = f2bf(a.y); r[2] = f2bf(a.z); r[3] = f2bf(a.w);
    r[4] = f2bf(b.x); r[5] = f2bf(b.y); r[6] = f2bf(b.z); r[7] = f2bf(b.w);
    *((ushort8*)out + i) = r;
}

// ---------------- generic B^T-form bf16 MFMA GEMM body ----------------
// C[m,n] = sum_k A[m,k]*B[n,k] (+bias[n]). BMxBN tile, BK=64, NWM x NWN waves
// (each wave owns (BM/NWM) x (BN/NWN)). XCD-aware bijective swizzle (NWG%8==0).
// bm varies fastest within an XCD chunk -> each XCD reuses a small B panel (L2).
template<bool BIAS, typename OUT_T, int MD, int ND, int KD,
         int BM, int BN, int NWM, int NWN>
__device__ __forceinline__ void gemm_bt_body(
    const unsigned short* __restrict__ A, const unsigned short* __restrict__ B,
    OUT_T* __restrict__ C, const float* __restrict__ bias, int id)
{
    constexpr int BK = 64;
    constexpr int THREADS = NWM * NWN * 64;
    constexpr int NBM = MD / BM, NBN = ND / BN, NWG = NBM * NBN;
    constexpr int CPX = NWG / 8;
    constexpr int WTM = BM / NWM, WTN = BN / NWN;
    constexpr int AM = WTM / 16, AN = WTN / 16;
    constexpr int RPP = THREADS / 8;     // staging rows per pass

    __shared__ unsigned short As[BM * BK];
    __shared__ unsigned short Bs[BN * BK];

    const int t = threadIdx.x;
    const int swz = (id & 7) * CPX + (id >> 3);
    const int bm = swz % NBM, bn = swz / NBM;

    const int lane = t & 63, wave = t >> 6;
    const int wr = wave / NWN, wc = wave % NWN;

    const int rsub = t >> 3;          // 0..RPP-1
    const int kb   = (t & 7) * 8;     // bf16-elem offset within BK

    const unsigned short* Ag = A + (size_t)(bm * BM + rsub) * KD + kb;
    const unsigned short* Bg = B + (size_t)(bn * BN + rsub) * KD + kb;

    f32x4 acc[AM][AN] = {};

    for (int k0 = 0; k0 < KD; k0 += BK) {
        __syncthreads();
        #pragma unroll
        for (int p = 0; p < BM / RPP; ++p)
            async_load16(Ag + (size_t)(p * RPP) * KD + k0, &As[(rsub + p * RPP) * BK + kb]);
        #pragma unroll
        for (int p = 0; p < BN / RPP; ++p)
            async_load16(Bg + (size_t)(p * RPP) * KD + k0, &Bs[(rsub + p * RPP) * BK + kb]);
        __syncthreads();   // compiler emits vmcnt(0) drain before barrier

        #pragma unroll
        for (int ks = 0; ks < 2; ++ks) {
            bf16x8 a[AM], b[AN];
            #pragma unroll
            for (int mi = 0; mi < AM; ++mi)
                a[mi] = *(const bf16x8*)&As[(wr * WTM + mi * 16 + (lane & 15)) * BK + ks * 32 + (lane >> 4) * 8];
            #pragma unroll
            for (int ni = 0; ni < AN; ++ni)
                b[ni] = *(const bf16x8*)&Bs[(wc * WTN + ni * 16 + (lane & 15)) * BK + ks * 32 + (lane >> 4) * 8];
            #pragma unroll
            for (int mi = 0; mi < AM; ++mi)
                #pragma unroll
                for (int ni = 0; ni < AN; ++ni)
                    acc[mi][ni] = __builtin_amdgcn_mfma_f32_16x16x32_bf16(
                        a[mi], b[ni], acc[mi][ni], 0, 0, 0);
        }
    }

    // C/D layout (m89/m91): col = lane&15, row = (lane>>4)*4 + reg.
    const int crow0 = bm * BM + wr * WTM + (lane >> 4) * 4;
    const int ccol0 = bn * BN + wc * WTN + (lane & 15);
    #pragma unroll
    for (int mi = 0; mi < AM; ++mi) {
        #pragma unroll
        for (int ni = 0; ni < AN; ++ni) {
            const int col = ccol0 + ni * 16;
            float bv = 0.f;
            if constexpr (BIAS) bv = bias[col];
            #pragma unroll
            for (int i = 0; i < 4; ++i) {
                const int row = crow0 + mi * 16 + i;
                float val = acc[mi][ni][i] + bv;
                if constexpr (std::is_same<OUT_T, float>::value)
                    C[(size_t)row * ND + col] = val;
                else
                    C[(size_t)row * ND + col] = f2bf(val);
            }
        }
    }
}

// ---------------- K1: weight prep ----------------
// blocks [0,256):   WvT[e,k] = bf16(Wqkv[vrow(k), e])  (16x16 tiles of 64x64)
// blocks [256,768): Wo -> bf16
// blocks [768,784): c[i] = bo[i] + sum_k Wo[i,k]*bqkv[vrow(k)]
__global__ __launch_bounds__(256) void prep_w(
    const float* __restrict__ Wqkv, const float* __restrict__ bqkv,
    const float* __restrict__ Wo, const float* __restrict__ bo,
    unsigned short* __restrict__ WvT, unsigned short* __restrict__ wo_bf,
    float* __restrict__ c)
{
    const int blk = blockIdx.x;
    const int t = threadIdx.x;
    if (blk < 256) {                        // ---- build WvT ----
        __shared__ unsigned short tile[64][65];
        const int eBase = (blk & 15) * 64, kBase = (blk >> 4) * 64;
        const int tx = t & 63, ty = t >> 6;
        #pragma unroll
        for (int r = ty; r < 64; r += 4) {
            int k = kBase + r;
            int j = ((k >> 6) * 192) + 128 + (k & 63);   // vrow(k)
            tile[r][tx] = f2bf(Wqkv[(size_t)j * EDIM + eBase + tx]);
        }
        __syncthreads();
        #pragma unroll
        for (int r = ty; r < 64; r += 4)
            WvT[(size_t)(eBase + r) * EDIM + kBase + tx] = tile[tx][r];
    } else if (blk < 768) {                 // ---- cast Wo ----
        cast8(Wo, wo_bf, (blk - 256) * 256 + t);
    } else {                                // ---- fused bias c ----
        const int b = blk - 768;            // 0..15
        const int wave = t >> 6, lane = t & 63;
        for (int r = 0; r < 16; ++r) {
            int row = b * 64 + wave * 16 + r;
            float s = 0.f;
            #pragma unroll
            for (int kk = 0; kk < 16; ++kk) {
                int k = kk * 64 + lane;
                int j = kk * 192 + 128 + lane;   // vrow(k)
                s += Wo[(size_t)row * EDIM + k] * bqkv[j];
            }
            #pragma unroll
            for (int off = 32; off > 0; off >>= 1) s += __shfl_down(s, off);
            if (lane == 0) c[row] = s + bo[row];
        }
    }
}

// ---------------- K2: gemm1 (M = Wo @ Wv_sub) co-dispatched with cast_x ----------------
// blocks [0,128):    M GEMM, 64x128 tiles (16x8 grid)
// blocks [128,2176): x -> bf16 (4M elems, 2048 elems/block)
__global__ __launch_bounds__(256) void gemm1_castx(
    const unsigned short* __restrict__ wo_bf, const unsigned short* __restrict__ wvt,
    unsigned short* __restrict__ m_bf,
    const float* __restrict__ x, unsigned short* __restrict__ x_bf)
{
    const int blk = blockIdx.x;
    if (blk < 128) {
        gemm_bt_body<false, unsigned short, EDIM, EDIM, EDIM, 64, 128, 2, 2>(
            wo_bf, wvt, m_bf, nullptr, blk);
    } else {
        cast8(x, x_bf, (blk - 128) * 256 + threadIdx.x);
    }
}

// ---------------- K3: out = x @ M^T + c ----------------
// 128x64 tiles -> 32x16 grid = 512 blocks = 2+ blocks/CU (barrier-drain overlap).
__global__ __launch_bounds__(256, 4) void gemm2(
    const unsigned short* __restrict__ x_bf, const unsigned short* __restrict__ m_bf,
    float* __restrict__ out, const float* __restrict__ cvec)
{
    gemm_bt_body<true, float, MROWS, EDIM, EDIM, 128, 64, 2, 2>(
        x_bf, m_bf, out, cvec, blockIdx.x);
}

extern "C" void kernel_launch(void* const* d_in, const int* in_sizes, int n_in,
                              void* d_out, int out_size, void* d_ws, size_t ws_size,
                              hipStream_t stream) {
    const float* x    = (const float*)d_in[0];   // (2,2048,1024)
    const float* Wqkv = (const float*)d_in[1];   // (3072,1024)
    const float* bqkv = (const float*)d_in[2];   // (3072,)
    const float* Wo   = (const float*)d_in[3];   // (1024,1024)
    const float* bo   = (const float*)d_in[4];   // (1024,)
    float* out = (float*)d_out;                  // (2,2048,1024) f32

    char* ws = (char*)d_ws;
    unsigned short* x_bf  = (unsigned short*)(ws);                       // 8 MB
    unsigned short* wvt   = (unsigned short*)(ws + 8u  * 1024 * 1024);   // 2 MB
    unsigned short* wo_bf = (unsigned short*)(ws + 10u * 1024 * 1024);   // 2 MB
    unsigned short* m_bf  = (unsigned short*)(ws + 12u * 1024 * 1024);   // 2 MB
    float*          cvec  = (float*)(ws + 14u * 1024 * 1024);            // 4 KB

    // K1: weight prep (WvT gather/transpose, Wo cast, fused bias c)
    prep_w<<<784, 256, 0, stream>>>(Wqkv, bqkv, Wo, bo, wvt, wo_bf, cvec);
    // K2: M = Wo @ Wv_sub  (128 blocks)  ||  x -> bf16 (2048 blocks)
    gemm1_castx<<<2176, 256, 0, stream>>>(wo_bf, wvt, m_bf, x, x_bf);
    // K3: out = x @ M^T + c
    gemm2<<<512, 256, 0, stream>>>(x_bf, m_bf, out, cvec);
}